// Round 12
// baseline (1099.319 us; speedup 1.0000x reference)
//
#include <hip/hip_runtime.h>
#include <math.h>

// Capsule routing, no u_hat materialization.
// Round 12: k_route attacked via LDS-READ COUNT (new model: 768 b128 reads/thread
// x 12cyc on one LDS pipe/CU ≈ 30µs = the 43µs floor's cause).
//   phase 1: 8x8 register tile, k-split-4 + shfl reduce -> 16 FMA/read (2x R2).
//   phase 3: 4n x 8d tile -> 1 cl read per 32 FMA (2x).
// Staging/barriers/layout/LDS bytes VERBATIM R2. k_ot/k_sumu identical to R11.
// Workspace 18.5 MB (proven envelope).

#define B   64
#define IN  1024
#define ID  256
#define NC  32
#define DC  64

// ---------------------------------------------------------------------------
// sp0[c][b][d] = sum over i-chunk c of u[b][i][d]   (8 chunks of 128 i)
__global__ __launch_bounds__(256) void k_sumu(const float* __restrict__ u,
                                              float* __restrict__ sp0) {
    const int c = blockIdx.x, b = blockIdx.y;
    const int tid = threadIdx.x;
    const int d4 = tid & 63, ig = tid >> 6;
    __shared__ float4 part[4][64];
    const float* up = u + ((size_t)b * IN + (size_t)c * (IN / 8) + ig) * ID + d4 * 4;
    float4 a = make_float4(0.f, 0.f, 0.f, 0.f);
#pragma unroll 8
    for (int i = 0; i < 32; ++i) {
        const float4 v = *(const float4*)(up + (size_t)i * 4 * ID);
        a.x += v.x; a.y += v.y; a.z += v.z; a.w += v.w;
    }
    part[ig][d4] = a;
    __syncthreads();
    if (tid < 64) {
        const float4 t0 = part[0][tid], t1 = part[1][tid];
        const float4 t2 = part[2][tid], t3 = part[3][tid];
        const float4 r = make_float4(t0.x + t1.x + t2.x + t3.x,
                                     t0.y + t1.y + t2.y + t3.y,
                                     t0.z + t1.z + t2.z + t3.z,
                                     t0.w + t1.w + t2.w + t3.w);
        *(float4*)&sp0[(size_t)(c * B + b) * ID + tid * 4] = r;
    }
}

// ---------------------------------------------------------------------------
// Batched o/t kernel (R11, matched prediction): block = (n, bq), 4 b's/block.
__global__ __launch_bounds__(256) void k_ot(const float* __restrict__ W,
                                            const float* __restrict__ src,
                                            float* __restrict__ tout,
                                            const int mode) {
    const int n  = blockIdx.x & (NC - 1);
    const int bq = blockIdx.x >> 5;          // 0..15
    const int tid = threadIdx.x;
    __shared__ __align__(16) float s_lds[4][ID];
    __shared__ float o_lds[4][DC];
    __shared__ float red[4][DC];

#pragma unroll
    for (int m = 0; m < 4; ++m) {
        const int b = bq + m * 16;
        float sv = 0.f;
        if (mode == 0) {
#pragma unroll
            for (int c = 0; c < 8; ++c) sv += src[(size_t)(c * B + b) * ID + tid];
            sv *= (1.0f / NC);
        } else {
#pragma unroll
            for (int c = 0; c < 8; ++c)
                sv += src[((size_t)(c * B + b) * NC + n) * ID + tid];
        }
        s_lds[m][tid] = sv;
    }
    __syncthreads();

    const int g = tid >> 2, j = tid & 3;
    const float* wrow = W + ((size_t)n * DC + g) * ID;
    float p[4] = {0.f, 0.f, 0.f, 0.f};
#pragma unroll
    for (int kk = 0; kk < 16; ++kk) {
        const int k = (kk * 4 + j) * 4;
        const float4 wv = *(const float4*)(wrow + k);
#pragma unroll
        for (int m = 0; m < 4; ++m) {
            const float4 s4 = *(const float4*)(&s_lds[m][k]);
            p[m] += wv.x * s4.x + wv.y * s4.y + wv.z * s4.z + wv.w * s4.w;
        }
    }
#pragma unroll
    for (int m = 0; m < 4; ++m) {
        p[m] += __shfl_xor(p[m], 1);
        p[m] += __shfl_xor(p[m], 2);
    }
    if (j == 0) {
#pragma unroll
        for (int m = 0; m < 4; ++m) { o_lds[m][g] = p[m]; red[m][g] = p[m] * p[m]; }
    }
    __syncthreads();

    const int w = tid >> 6, lane = tid & 63;
    {
        float q = red[w][lane];
#pragma unroll
        for (int off = 32; off > 0; off >>= 1) q += __shfl_down(q, off);
        q = __shfl(q, 0);
        if (mode == 2) {
            const float sq = q + 1e-7f;
            const float sc = sqrtf(sq) / (0.5f + sq);
            const int b = bq + w * 16;
            tout[(size_t)(b * NC + n) * DC + lane] = o_lds[w][lane] * sc;
        } else {
            const float inv = 1.0f / fmaxf(sqrtf(q), 1e-12f);
            o_lds[w][lane] *= inv;
        }
    }
    if (mode == 2) return;
    __syncthreads();

    float acc[4] = {0.f, 0.f, 0.f, 0.f};
    const float* wc = W + (size_t)n * DC * ID + tid;
#pragma unroll 8
    for (int d = 0; d < DC; ++d) {
        const float wv = wc[(size_t)d * ID];
#pragma unroll
        for (int m = 0; m < 4; ++m) acc[m] += wv * o_lds[m][d];
    }
#pragma unroll
    for (int m = 0; m < 4; ++m) {
        const int b = bq + m * 16;
        tout[((size_t)b * NC + n) * ID + tid] = acc[m];
    }
}

// ---------------------------------------------------------------------------
// Fused routing step. R2 staging/barriers/layout; register tiles widened:
//   phase 1: thread (s,gi,gn) owns 8i x 8n at k-slice s (of 4); per k:
//            2 a-reads + 2 b-reads -> 64 FMA. shfl_xor(1,2) reduces slices.
//   phase 2: softmax (unchanged).
//   phase 3: thread (ng8,dg) owns 4n x 8d; per i: 1 cl read + 2 global.
#define RTILE 128
__global__ __launch_bounds__(256) void k_route(const float* __restrict__ u,
                                               const float* __restrict__ t,
                                               float* __restrict__ sp) {
    const int it = blockIdx.x, b = blockIdx.y;
    const int iBase = it * RTILE;
    __shared__ float Ts[ID][36];      // t[b] transposed: Ts[k][n]  (36.9 KB)
    __shared__ float Us[16][132];     // u chunk transposed: Us[k][i] (8.4 KB)
    __shared__ float cl[RTILE][36];   // logits -> softmax coeffs   (18.4 KB)
    const int tid = threadIdx.x;

    // load full Ts (one-time): thread=k, loop n. Global coalesced.
    {
        const float* tb = t + (size_t)b * NC * ID;
#pragma unroll
        for (int n = 0; n < NC; ++n) Ts[tid][n] = tb[(size_t)n * ID + tid];
    }

    // ---- phase 1: logits, 8x8 tile, k-split-4 ----
    const int s  = tid & 3;          // k-slice (4 k of each 16-chunk)
    const int g  = tid >> 2;         // 64 output groups
    const int gi = g >> 2;           // 0..15 : i0 = gi*8
    const int gn = g & 3;            // 0..3  : n0 = gn*8
    const int i0 = gi * 8, n0 = gn * 8;
    float acc[8][8] = {{0.f}};
    const float* ub = u + ((size_t)b * IN + iBase) * ID;

    for (int kc = 0; kc < ID / 16; ++kc) {
        __syncthreads();   // Ts ready (first iter) / prior chunk consumed
#pragma unroll
        for (int rep = 0; rep < 2; ++rep) {
            const int f = tid + rep * 256;
            const int i = f >> 2, c4 = f & 3;
            const float4 v = *(const float4*)(ub + (size_t)i * ID + kc * 16 + c4 * 4);
            Us[c4 * 4 + 0][i] = v.x;
            Us[c4 * 4 + 1][i] = v.y;
            Us[c4 * 4 + 2][i] = v.z;
            Us[c4 * 4 + 3][i] = v.w;
        }
        __syncthreads();
#pragma unroll
        for (int kk = 0; kk < 4; ++kk) {
            const int lk = s * 4 + kk;
            const float4 a0 = *(const float4*)&Us[lk][i0];
            const float4 a1 = *(const float4*)&Us[lk][i0 + 4];
            const float4 b0 = *(const float4*)&Ts[kc * 16 + lk][n0];
            const float4 b1 = *(const float4*)&Ts[kc * 16 + lk][n0 + 4];
            const float av[8] = {a0.x, a0.y, a0.z, a0.w, a1.x, a1.y, a1.z, a1.w};
            const float bv[8] = {b0.x, b0.y, b0.z, b0.w, b1.x, b1.y, b1.z, b1.w};
#pragma unroll
            for (int ii = 0; ii < 8; ++ii)
#pragma unroll
                for (int jj = 0; jj < 8; ++jj) acc[ii][jj] += av[ii] * bv[jj];
        }
    }

    // reduce the four k-slices (lanes differ in bits 0-1)
#pragma unroll
    for (int ii = 0; ii < 8; ++ii)
#pragma unroll
        for (int jj = 0; jj < 8; ++jj) {
            acc[ii][jj] += __shfl_xor(acc[ii][jj], 1);
            acc[ii][jj] += __shfl_xor(acc[ii][jj], 2);
        }

    // slice s writes rows i0+2s, i0+2s+1 (disjoint full coverage)
#pragma unroll
    for (int v = 0; v < 2; ++v) {
        const int ii = 2 * s + v;
        *(float4*)&cl[i0 + ii][n0] =
            make_float4(acc[ii][0], acc[ii][1], acc[ii][2], acc[ii][3]);
        *(float4*)&cl[i0 + ii][n0 + 4] =
            make_float4(acc[ii][4], acc[ii][5], acc[ii][6], acc[ii][7]);
    }
    __syncthreads();

    // ---- phase 2: softmax over 32 n; 2 threads per i (16 n each) ----
    {
        const int i = tid >> 1, half = tid & 1;
        float v[16];
#pragma unroll
        for (int j = 0; j < 16; ++j) v[j] = cl[i][half * 16 + j];
        float mx = v[0];
#pragma unroll
        for (int j = 1; j < 16; ++j) mx = fmaxf(mx, v[j]);
        mx = fmaxf(mx, __shfl_xor(mx, 1));
        float sum = 0.f;
#pragma unroll
        for (int j = 0; j < 16; ++j) { v[j] = __expf(v[j] - mx); sum += v[j]; }
        sum += __shfl_xor(sum, 1);
        const float inv = 1.0f / sum;
#pragma unroll
        for (int j = 0; j < 16; ++j) cl[i][half * 16 + j] = v[j] * inv;
    }
    __syncthreads();

    // ---- phase 3: weighted aggregation, 4n x 8d tile ----
    const int dg  = tid & 31;      // d base = dg*8
    const int ng8 = tid >> 5;      // n base = ng8*4
    float a2[4][8] = {{0.f}};
    const float* ur = ub + dg * 8;
#pragma unroll 4
    for (int i = 0; i < RTILE; ++i) {
        const float4 uv0 = *(const float4*)(ur + (size_t)i * ID);
        const float4 uv1 = *(const float4*)(ur + (size_t)i * ID + 4);
        const float4 c0 = *(const float4*)&cl[i][ng8 * 4];
        const float cv[4] = {c0.x, c0.y, c0.z, c0.w};
        const float uvv[8] = {uv0.x, uv0.y, uv0.z, uv0.w,
                              uv1.x, uv1.y, uv1.z, uv1.w};
#pragma unroll
        for (int j = 0; j < 4; ++j)
#pragma unroll
            for (int x = 0; x < 8; ++x) a2[j][x] += cv[j] * uvv[x];
    }

    float* spb = sp + (size_t)(it * B + b) * NC * ID;
#pragma unroll
    for (int j = 0; j < 4; ++j) {
        const int n = ng8 * 4 + j;
        *(float4*)&spb[(size_t)n * ID + dg * 8] =
            make_float4(a2[j][0], a2[j][1], a2[j][2], a2[j][3]);
        *(float4*)&spb[(size_t)n * ID + dg * 8 + 4] =
            make_float4(a2[j][4], a2[j][5], a2[j][6], a2[j][7]);
    }
}

// ---------------------------------------------------------------------------
extern "C" void kernel_launch(void* const* d_in, const int* in_sizes, int n_in,
                              void* d_out, int out_size, void* d_ws, size_t ws_size,
                              hipStream_t stream) {
    const float* u = (const float*)d_in[0];   // [B][IN][ID]
    const float* W = (const float*)d_in[1];   // [NC*DC][ID]
    float* out = (float*)d_out;               // [B][NC][DC]

    float* ws  = (float*)d_ws;
    float* t   = ws;                                   // B*NC*ID      = 0.5M floats
    float* sp  = t + (size_t)B * NC * ID;              // 8*B*NC*ID    = 4M floats
    float* sp0 = sp + (size_t)8 * B * NC * ID;         // 8*B*ID       = 128K floats

    const dim3 blk(256);

    // routing iteration 0 (c uniform = 1/32)
    k_sumu <<<dim3(8, B), blk, 0, stream>>>(u, sp0);
    k_ot   <<<dim3(NC * (B / 4)), blk, 0, stream>>>(W, sp0, t, 0);
    // iteration 1 (logits + softmax + aggregate fused)
    k_route<<<dim3(IN / RTILE, B), blk, 0, stream>>>(u, t, sp);
    k_ot   <<<dim3(NC * (B / 4)), blk, 0, stream>>>(W, sp, t, 1);
    // iteration 2
    k_route<<<dim3(IN / RTILE, B), blk, 0, stream>>>(u, t, sp);
    k_ot   <<<dim3(NC * (B / 4)), blk, 0, stream>>>(W, sp, out, 2);
}

// Round 13
// 198.587 us; speedup vs baseline: 5.5357x; 5.5357x over previous
//
#include <hip/hip_runtime.h>
#include <math.h>

// Capsule routing, no u_hat materialization.
// Round 13: R12's 8x8-tile k_route WITH THE SPILL FIXED. R12's 515µs was
// rule #20: `acc[2*s+v]` (runtime s) demoted acc[8][8] to scratch
// (VGPR=88 < 64 needed; WRITE_SIZE 1 GB = spill traffic). Fix: the cl-write
// uses four statically-indexed branches. Everything else identical to R12.
// Workspace 18.5 MB (proven envelope).

#define B   64
#define IN  1024
#define ID  256
#define NC  32
#define DC  64

// ---------------------------------------------------------------------------
// sp0[c][b][d] = sum over i-chunk c of u[b][i][d]   (8 chunks of 128 i)
__global__ __launch_bounds__(256) void k_sumu(const float* __restrict__ u,
                                              float* __restrict__ sp0) {
    const int c = blockIdx.x, b = blockIdx.y;
    const int tid = threadIdx.x;
    const int d4 = tid & 63, ig = tid >> 6;
    __shared__ float4 part[4][64];
    const float* up = u + ((size_t)b * IN + (size_t)c * (IN / 8) + ig) * ID + d4 * 4;
    float4 a = make_float4(0.f, 0.f, 0.f, 0.f);
#pragma unroll 8
    for (int i = 0; i < 32; ++i) {
        const float4 v = *(const float4*)(up + (size_t)i * 4 * ID);
        a.x += v.x; a.y += v.y; a.z += v.z; a.w += v.w;
    }
    part[ig][d4] = a;
    __syncthreads();
    if (tid < 64) {
        const float4 t0 = part[0][tid], t1 = part[1][tid];
        const float4 t2 = part[2][tid], t3 = part[3][tid];
        const float4 r = make_float4(t0.x + t1.x + t2.x + t3.x,
                                     t0.y + t1.y + t2.y + t3.y,
                                     t0.z + t1.z + t2.z + t3.z,
                                     t0.w + t1.w + t2.w + t3.w);
        *(float4*)&sp0[(size_t)(c * B + b) * ID + tid * 4] = r;
    }
}

// ---------------------------------------------------------------------------
// Batched o/t kernel (R11, matched prediction): block = (n, bq), 4 b's/block.
__global__ __launch_bounds__(256) void k_ot(const float* __restrict__ W,
                                            const float* __restrict__ src,
                                            float* __restrict__ tout,
                                            const int mode) {
    const int n  = blockIdx.x & (NC - 1);
    const int bq = blockIdx.x >> 5;          // 0..15
    const int tid = threadIdx.x;
    __shared__ __align__(16) float s_lds[4][ID];
    __shared__ float o_lds[4][DC];
    __shared__ float red[4][DC];

#pragma unroll
    for (int m = 0; m < 4; ++m) {
        const int b = bq + m * 16;
        float sv = 0.f;
        if (mode == 0) {
#pragma unroll
            for (int c = 0; c < 8; ++c) sv += src[(size_t)(c * B + b) * ID + tid];
            sv *= (1.0f / NC);
        } else {
#pragma unroll
            for (int c = 0; c < 8; ++c)
                sv += src[((size_t)(c * B + b) * NC + n) * ID + tid];
        }
        s_lds[m][tid] = sv;
    }
    __syncthreads();

    const int g = tid >> 2, j = tid & 3;
    const float* wrow = W + ((size_t)n * DC + g) * ID;
    float p[4] = {0.f, 0.f, 0.f, 0.f};
#pragma unroll
    for (int kk = 0; kk < 16; ++kk) {
        const int k = (kk * 4 + j) * 4;
        const float4 wv = *(const float4*)(wrow + k);
#pragma unroll
        for (int m = 0; m < 4; ++m) {
            const float4 s4 = *(const float4*)(&s_lds[m][k]);
            p[m] += wv.x * s4.x + wv.y * s4.y + wv.z * s4.z + wv.w * s4.w;
        }
    }
#pragma unroll
    for (int m = 0; m < 4; ++m) {
        p[m] += __shfl_xor(p[m], 1);
        p[m] += __shfl_xor(p[m], 2);
    }
    if (j == 0) {
#pragma unroll
        for (int m = 0; m < 4; ++m) { o_lds[m][g] = p[m]; red[m][g] = p[m] * p[m]; }
    }
    __syncthreads();

    const int w = tid >> 6, lane = tid & 63;
    {
        float q = red[w][lane];
#pragma unroll
        for (int off = 32; off > 0; off >>= 1) q += __shfl_down(q, off);
        q = __shfl(q, 0);
        if (mode == 2) {
            const float sq = q + 1e-7f;
            const float sc = sqrtf(sq) / (0.5f + sq);
            const int b = bq + w * 16;
            tout[(size_t)(b * NC + n) * DC + lane] = o_lds[w][lane] * sc;
        } else {
            const float inv = 1.0f / fmaxf(sqrtf(q), 1e-12f);
            o_lds[w][lane] *= inv;
        }
    }
    if (mode == 2) return;
    __syncthreads();

    float acc[4] = {0.f, 0.f, 0.f, 0.f};
    const float* wc = W + (size_t)n * DC * ID + tid;
#pragma unroll 8
    for (int d = 0; d < DC; ++d) {
        const float wv = wc[(size_t)d * ID];
#pragma unroll
        for (int m = 0; m < 4; ++m) acc[m] += wv * o_lds[m][d];
    }
#pragma unroll
    for (int m = 0; m < 4; ++m) {
        const int b = bq + m * 16;
        tout[((size_t)b * NC + n) * ID + tid] = acc[m];
    }
}

// ---------------------------------------------------------------------------
// Fused routing step. R2 staging/barriers/layout; register tiles widened:
//   phase 1: thread (s,gi,gn) owns 8i x 8n at k-slice s (of 4); per k:
//            2 a-reads + 2 b-reads -> 64 FMA. shfl_xor(1,2) reduces slices.
//            cl-write: STATIC branches per slice (rule #20 — no runtime idx).
//   phase 2: softmax (unchanged).
//   phase 3: thread (ng8,dg) owns 4n x 8d; per i: 1 cl read + 2 global.
#define RTILE 128

#define WRITE_CL_ROW(II)                                                       \
    do {                                                                       \
        *(float4*)&cl[i0 + (II)][n0] =                                         \
            make_float4(acc[(II)][0], acc[(II)][1], acc[(II)][2], acc[(II)][3]); \
        *(float4*)&cl[i0 + (II)][n0 + 4] =                                     \
            make_float4(acc[(II)][4], acc[(II)][5], acc[(II)][6], acc[(II)][7]); \
    } while (0)

__global__ __launch_bounds__(256) void k_route(const float* __restrict__ u,
                                               const float* __restrict__ t,
                                               float* __restrict__ sp) {
    const int it = blockIdx.x, b = blockIdx.y;
    const int iBase = it * RTILE;
    __shared__ float Ts[ID][36];      // t[b] transposed: Ts[k][n]  (36.9 KB)
    __shared__ float Us[16][132];     // u chunk transposed: Us[k][i] (8.4 KB)
    __shared__ float cl[RTILE][36];   // logits -> softmax coeffs   (18.4 KB)
    const int tid = threadIdx.x;

    // load full Ts (one-time): thread=k, loop n. Global coalesced.
    {
        const float* tb = t + (size_t)b * NC * ID;
#pragma unroll
        for (int n = 0; n < NC; ++n) Ts[tid][n] = tb[(size_t)n * ID + tid];
    }

    // ---- phase 1: logits, 8x8 tile, k-split-4 ----
    const int s  = tid & 3;          // k-slice (4 k of each 16-chunk)
    const int g  = tid >> 2;         // 64 output groups
    const int gi = g >> 2;           // 0..15 : i0 = gi*8
    const int gn = g & 3;            // 0..3  : n0 = gn*8
    const int i0 = gi * 8, n0 = gn * 8;
    float acc[8][8] = {{0.f}};
    const float* ub = u + ((size_t)b * IN + iBase) * ID;

    for (int kc = 0; kc < ID / 16; ++kc) {
        __syncthreads();   // Ts ready (first iter) / prior chunk consumed
#pragma unroll
        for (int rep = 0; rep < 2; ++rep) {
            const int f = tid + rep * 256;
            const int i = f >> 2, c4 = f & 3;
            const float4 v = *(const float4*)(ub + (size_t)i * ID + kc * 16 + c4 * 4);
            Us[c4 * 4 + 0][i] = v.x;
            Us[c4 * 4 + 1][i] = v.y;
            Us[c4 * 4 + 2][i] = v.z;
            Us[c4 * 4 + 3][i] = v.w;
        }
        __syncthreads();
#pragma unroll
        for (int kk = 0; kk < 4; ++kk) {
            const int lk = s * 4 + kk;
            const float4 a0 = *(const float4*)&Us[lk][i0];
            const float4 a1 = *(const float4*)&Us[lk][i0 + 4];
            const float4 b0 = *(const float4*)&Ts[kc * 16 + lk][n0];
            const float4 b1 = *(const float4*)&Ts[kc * 16 + lk][n0 + 4];
            const float av[8] = {a0.x, a0.y, a0.z, a0.w, a1.x, a1.y, a1.z, a1.w};
            const float bv[8] = {b0.x, b0.y, b0.z, b0.w, b1.x, b1.y, b1.z, b1.w};
#pragma unroll
            for (int ii = 0; ii < 8; ++ii)
#pragma unroll
                for (int jj = 0; jj < 8; ++jj) acc[ii][jj] += av[ii] * bv[jj];
        }
    }

    // reduce the four k-slices (lanes differ in bits 0-1)
#pragma unroll
    for (int ii = 0; ii < 8; ++ii)
#pragma unroll
        for (int jj = 0; jj < 8; ++jj) {
            acc[ii][jj] += __shfl_xor(acc[ii][jj], 1);
            acc[ii][jj] += __shfl_xor(acc[ii][jj], 2);
        }

    // slice s writes rows i0+2s, i0+2s+1 — STATIC indices per branch (rule #20)
    if (s == 0)      { WRITE_CL_ROW(0); WRITE_CL_ROW(1); }
    else if (s == 1) { WRITE_CL_ROW(2); WRITE_CL_ROW(3); }
    else if (s == 2) { WRITE_CL_ROW(4); WRITE_CL_ROW(5); }
    else             { WRITE_CL_ROW(6); WRITE_CL_ROW(7); }
    __syncthreads();

    // ---- phase 2: softmax over 32 n; 2 threads per i (16 n each) ----
    {
        const int i = tid >> 1, half = tid & 1;
        float v[16];
#pragma unroll
        for (int j = 0; j < 16; ++j) v[j] = cl[i][half * 16 + j];
        float mx = v[0];
#pragma unroll
        for (int j = 1; j < 16; ++j) mx = fmaxf(mx, v[j]);
        mx = fmaxf(mx, __shfl_xor(mx, 1));
        float sum = 0.f;
#pragma unroll
        for (int j = 0; j < 16; ++j) { v[j] = __expf(v[j] - mx); sum += v[j]; }
        sum += __shfl_xor(sum, 1);
        const float inv = 1.0f / sum;
#pragma unroll
        for (int j = 0; j < 16; ++j) cl[i][half * 16 + j] = v[j] * inv;
    }
    __syncthreads();

    // ---- phase 3: weighted aggregation, 4n x 8d tile ----
    const int dg  = tid & 31;      // d base = dg*8
    const int ng8 = tid >> 5;      // n base = ng8*4
    float a2[4][8] = {{0.f}};
    const float* ur = ub + dg * 8;
#pragma unroll 4
    for (int i = 0; i < RTILE; ++i) {
        const float4 uv0 = *(const float4*)(ur + (size_t)i * ID);
        const float4 uv1 = *(const float4*)(ur + (size_t)i * ID + 4);
        const float4 c0 = *(const float4*)&cl[i][ng8 * 4];
        const float cv[4] = {c0.x, c0.y, c0.z, c0.w};
        const float uvv[8] = {uv0.x, uv0.y, uv0.z, uv0.w,
                              uv1.x, uv1.y, uv1.z, uv1.w};
#pragma unroll
        for (int j = 0; j < 4; ++j)
#pragma unroll
            for (int x = 0; x < 8; ++x) a2[j][x] += cv[j] * uvv[x];
    }

    float* spb = sp + (size_t)(it * B + b) * NC * ID;
#pragma unroll
    for (int j = 0; j < 4; ++j) {
        const int n = ng8 * 4 + j;
        *(float4*)&spb[(size_t)n * ID + dg * 8] =
            make_float4(a2[j][0], a2[j][1], a2[j][2], a2[j][3]);
        *(float4*)&spb[(size_t)n * ID + dg * 8 + 4] =
            make_float4(a2[j][4], a2[j][5], a2[j][6], a2[j][7]);
    }
}

// ---------------------------------------------------------------------------
extern "C" void kernel_launch(void* const* d_in, const int* in_sizes, int n_in,
                              void* d_out, int out_size, void* d_ws, size_t ws_size,
                              hipStream_t stream) {
    const float* u = (const float*)d_in[0];   // [B][IN][ID]
    const float* W = (const float*)d_in[1];   // [NC*DC][ID]
    float* out = (float*)d_out;               // [B][NC][DC]

    float* ws  = (float*)d_ws;
    float* t   = ws;                                   // B*NC*ID      = 0.5M floats
    float* sp  = t + (size_t)B * NC * ID;              // 8*B*NC*ID    = 4M floats
    float* sp0 = sp + (size_t)8 * B * NC * ID;         // 8*B*ID       = 128K floats

    const dim3 blk(256);

    // routing iteration 0 (c uniform = 1/32)
    k_sumu <<<dim3(8, B), blk, 0, stream>>>(u, sp0);
    k_ot   <<<dim3(NC * (B / 4)), blk, 0, stream>>>(W, sp0, t, 0);
    // iteration 1 (logits + softmax + aggregate fused)
    k_route<<<dim3(IN / RTILE, B), blk, 0, stream>>>(u, t, sp);
    k_ot   <<<dim3(NC * (B / 4)), blk, 0, stream>>>(W, sp, t, 1);
    // iteration 2
    k_route<<<dim3(IN / RTILE, B), blk, 0, stream>>>(u, t, sp);
    k_ot   <<<dim3(NC * (B / 4)), blk, 0, stream>>>(W, sp, out, 2);
}

// Round 14
// 190.576 us; speedup vs baseline: 5.7684x; 1.0420x over previous
//
#include <hip/hip_runtime.h>
#include <math.h>

// Capsule routing, no u_hat materialization.
// Round 14: restore the measured-best configuration (R11, 190.8 µs) as the
// standing kernel. k_route = R2 body (43.0 µs — best of 7 structural variants;
// barrier/occupancy/LDS-read models all falsified by A/B). k_ot batched x4
// over b (matched prediction, -14 µs). k_sumu f4-vectorized.
// Workspace 18.5 MB (proven envelope).

#define B   64
#define IN  1024
#define ID  256
#define NC  32
#define DC  64

// ---------------------------------------------------------------------------
// sp0[c][b][d] = sum over i-chunk c of u[b][i][d]   (8 chunks of 128 i)
__global__ __launch_bounds__(256) void k_sumu(const float* __restrict__ u,
                                              float* __restrict__ sp0) {
    const int c = blockIdx.x, b = blockIdx.y;
    const int tid = threadIdx.x;
    const int d4 = tid & 63, ig = tid >> 6;
    __shared__ float4 part[4][64];
    const float* up = u + ((size_t)b * IN + (size_t)c * (IN / 8) + ig) * ID + d4 * 4;
    float4 a = make_float4(0.f, 0.f, 0.f, 0.f);
#pragma unroll 8
    for (int i = 0; i < 32; ++i) {
        const float4 v = *(const float4*)(up + (size_t)i * 4 * ID);
        a.x += v.x; a.y += v.y; a.z += v.z; a.w += v.w;
    }
    part[ig][d4] = a;
    __syncthreads();
    if (tid < 64) {
        const float4 t0 = part[0][tid], t1 = part[1][tid];
        const float4 t2 = part[2][tid], t3 = part[3][tid];
        const float4 r = make_float4(t0.x + t1.x + t2.x + t3.x,
                                     t0.y + t1.y + t2.y + t3.y,
                                     t0.z + t1.z + t2.z + t3.z,
                                     t0.w + t1.w + t2.w + t3.w);
        *(float4*)&sp0[(size_t)(c * B + b) * ID + tid * 4] = r;
    }
}

// ---------------------------------------------------------------------------
// Batched o/t kernel: block = (n, bq) handles b in {bq, bq+16, bq+32, bq+48}.
// Per (b,n): s = reduced partials; o = W_n s ; then
//   mode 0/1: normalize o, t = W_n^T o_norm ;  mode 2: squash(o) -> out
// W_n element loaded ONCE serves 4 tasks (register reuse) -> L2 traffic /4.
__global__ __launch_bounds__(256) void k_ot(const float* __restrict__ W,
                                            const float* __restrict__ src,
                                            float* __restrict__ tout,
                                            const int mode) {
    const int n  = blockIdx.x & (NC - 1);
    const int bq = blockIdx.x >> 5;          // 0..15
    const int tid = threadIdx.x;
    __shared__ __align__(16) float s_lds[4][ID];
    __shared__ float o_lds[4][DC];
    __shared__ float red[4][DC];

    // reduce partial sums into s_lds for the 4 b's (coalesced)
#pragma unroll
    for (int m = 0; m < 4; ++m) {
        const int b = bq + m * 16;
        float sv = 0.f;
        if (mode == 0) {
#pragma unroll
            for (int c = 0; c < 8; ++c) sv += src[(size_t)(c * B + b) * ID + tid];
            sv *= (1.0f / NC);
        } else {
#pragma unroll
            for (int c = 0; c < 8; ++c)
                sv += src[((size_t)(c * B + b) * NC + n) * ID + tid];
        }
        s_lds[m][tid] = sv;
    }
    __syncthreads();

    // o[d] = dot(W[n*DC+d, :], s) — group g=tid>>2 owns row d=g; lane j=tid&3
    // covers k in f4 chunks. wv loaded once, feeds 4 tasks.
    const int g = tid >> 2, j = tid & 3;
    const float* wrow = W + ((size_t)n * DC + g) * ID;
    float p[4] = {0.f, 0.f, 0.f, 0.f};
#pragma unroll
    for (int kk = 0; kk < 16; ++kk) {
        const int k = (kk * 4 + j) * 4;
        const float4 wv = *(const float4*)(wrow + k);
#pragma unroll
        for (int m = 0; m < 4; ++m) {
            const float4 s4 = *(const float4*)(&s_lds[m][k]);
            p[m] += wv.x * s4.x + wv.y * s4.y + wv.z * s4.z + wv.w * s4.w;
        }
    }
#pragma unroll
    for (int m = 0; m < 4; ++m) {
        p[m] += __shfl_xor(p[m], 1);
        p[m] += __shfl_xor(p[m], 2);
    }
    if (j == 0) {
#pragma unroll
        for (int m = 0; m < 4; ++m) { o_lds[m][g] = p[m]; red[m][g] = p[m] * p[m]; }
    }
    __syncthreads();

    // wave w finishes task m=w: ||o||^2 reduce, then squash-store or scale
    const int w = tid >> 6, lane = tid & 63;
    {
        float q = red[w][lane];
#pragma unroll
        for (int off = 32; off > 0; off >>= 1) q += __shfl_down(q, off);
        q = __shfl(q, 0);
        if (mode == 2) {
            const float sq = q + 1e-7f;
            const float sc = sqrtf(sq) / (0.5f + sq);
            const int b = bq + w * 16;
            tout[(size_t)(b * NC + n) * DC + lane] = o_lds[w][lane] * sc;
        } else {
            const float inv = 1.0f / fmaxf(sqrtf(q), 1e-12f);
            o_lds[w][lane] *= inv;     // on = normalized o
        }
    }
    if (mode == 2) return;
    __syncthreads();

    // t[k] = sum_d W[n*DC+d, k] * on[d] — thread per k, coalesced column walk;
    // each W element feeds 4 tasks.
    float acc[4] = {0.f, 0.f, 0.f, 0.f};
    const float* wc = W + (size_t)n * DC * ID + tid;
#pragma unroll 8
    for (int d = 0; d < DC; ++d) {
        const float wv = wc[(size_t)d * ID];
#pragma unroll
        for (int m = 0; m < 4; ++m) acc[m] += wv * o_lds[m][d];
    }
#pragma unroll
    for (int m = 0; m < 4; ++m) {
        const int b = bq + m * 16;
        tout[((size_t)b * NC + n) * ID + tid] = acc[m];
    }
}

// ---------------------------------------------------------------------------
// Fused per-iteration routing step (VERBATIM R2 body — measured best, 43.0 µs):
//   logits[i][n] = sum_d u[b,i,d] * t[b,n,d]   (in LDS, never to HBM)
//   c = softmax_n(logits)
//   sp[it][b][n][d] = sum_{i in tile} c[i][n] * u[b,i,d]
#define RTILE 128
__global__ __launch_bounds__(256) void k_route(const float* __restrict__ u,
                                               const float* __restrict__ t,
                                               float* __restrict__ sp) {
    const int it = blockIdx.x, b = blockIdx.y;
    const int iBase = it * RTILE;
    __shared__ float Ts[ID][36];      // t[b] transposed: Ts[k][n]  (36.9 KB)
    __shared__ float Us[16][132];     // u chunk transposed: Us[k][i] (8.4 KB)
    __shared__ float cl[RTILE][36];   // logits -> softmax coeffs   (18.4 KB)
    const int tid = threadIdx.x;

    // load full Ts (one-time): thread=k, loop n. Global coalesced.
    {
        const float* tb = t + (size_t)b * NC * ID;
#pragma unroll
        for (int n = 0; n < NC; ++n) Ts[tid][n] = tb[(size_t)n * ID + tid];
    }

    // ---- phase 1: logits ----
    const int q = tid >> 3;   // i-thread: i0 = q*4
    const int r = tid & 7;    // n-thread: n0 = r*4
    float acc[4][4] = {{0.f}};
    const float* ub = u + ((size_t)b * IN + iBase) * ID;

    for (int kc = 0; kc < ID / 16; ++kc) {
        __syncthreads();   // Ts ready (first iter) / prior chunk consumed
#pragma unroll
        for (int rep = 0; rep < 2; ++rep) {
            const int f = tid + rep * 256;
            const int i = f >> 2, c4 = f & 3;
            const float4 v = *(const float4*)(ub + (size_t)i * ID + kc * 16 + c4 * 4);
            Us[c4 * 4 + 0][i] = v.x;
            Us[c4 * 4 + 1][i] = v.y;
            Us[c4 * 4 + 2][i] = v.z;
            Us[c4 * 4 + 3][i] = v.w;
        }
        __syncthreads();
#pragma unroll
        for (int k = 0; k < 16; ++k) {
            const float4 a4 = *(const float4*)&Us[k][q * 4];
            const float4 b4 = *(const float4*)&Ts[kc * 16 + k][r * 4];
            const float av[4] = {a4.x, a4.y, a4.z, a4.w};
            const float bv[4] = {b4.x, b4.y, b4.z, b4.w};
#pragma unroll
            for (int ii = 0; ii < 4; ++ii)
#pragma unroll
                for (int jj = 0; jj < 4; ++jj) acc[ii][jj] += av[ii] * bv[jj];
        }
    }

    // logits -> LDS
#pragma unroll
    for (int ii = 0; ii < 4; ++ii)
        *(float4*)&cl[q * 4 + ii][r * 4] =
            make_float4(acc[ii][0], acc[ii][1], acc[ii][2], acc[ii][3]);
    __syncthreads();

    // ---- phase 2: softmax over 32 n; 2 threads per i (16 n each) ----
    {
        const int i = tid >> 1, half = tid & 1;
        float v[16];
#pragma unroll
        for (int j = 0; j < 16; ++j) v[j] = cl[i][half * 16 + j];
        float mx = v[0];
#pragma unroll
        for (int j = 1; j < 16; ++j) mx = fmaxf(mx, v[j]);
        mx = fmaxf(mx, __shfl_xor(mx, 1));
        float sum = 0.f;
#pragma unroll
        for (int j = 0; j < 16; ++j) { v[j] = __expf(v[j] - mx); sum += v[j]; }
        sum += __shfl_xor(sum, 1);
        const float inv = 1.0f / sum;
#pragma unroll
        for (int j = 0; j < 16; ++j) cl[i][half * 16 + j] = v[j] * inv;
    }
    __syncthreads();

    // ---- phase 3: weighted aggregation (u tile re-read, L2-hot) ----
    const int d4 = tid & 63;       // float4 index into ID
    const int ng = tid >> 6;       // n base = ng*8 (wave-uniform -> LDS broadcast)
    float a2[8][4] = {{0.f}};
    const float* ur = ub + d4 * 4;
#pragma unroll 4
    for (int i = 0; i < RTILE; ++i) {
        const float4 uv = *(const float4*)(ur + (size_t)i * ID);
        const float4 c0 = *(const float4*)&cl[i][ng * 8];
        const float4 c1 = *(const float4*)&cl[i][ng * 8 + 4];
        const float cv[8] = {c0.x, c0.y, c0.z, c0.w, c1.x, c1.y, c1.z, c1.w};
        const float uvv[4] = {uv.x, uv.y, uv.z, uv.w};
#pragma unroll
        for (int j = 0; j < 8; ++j)
#pragma unroll
            for (int x = 0; x < 4; ++x) a2[j][x] += cv[j] * uvv[x];
    }

    float* spb = sp + (size_t)(it * B + b) * NC * ID;
#pragma unroll
    for (int j = 0; j < 8; ++j) {
        const int n = ng * 8 + j;
        *(float4*)&spb[(size_t)n * ID + d4 * 4] =
            make_float4(a2[j][0], a2[j][1], a2[j][2], a2[j][3]);
    }
}

// ---------------------------------------------------------------------------
extern "C" void kernel_launch(void* const* d_in, const int* in_sizes, int n_in,
                              void* d_out, int out_size, void* d_ws, size_t ws_size,
                              hipStream_t stream) {
    const float* u = (const float*)d_in[0];   // [B][IN][ID]
    const float* W = (const float*)d_in[1];   // [NC*DC][ID]
    float* out = (float*)d_out;               // [B][NC][DC]

    float* ws  = (float*)d_ws;
    float* t   = ws;                                   // B*NC*ID      = 0.5M floats
    float* sp  = t + (size_t)B * NC * ID;              // 8*B*NC*ID    = 4M floats
    float* sp0 = sp + (size_t)8 * B * NC * ID;         // 8*B*ID       = 128K floats

    const dim3 blk(256);

    // routing iteration 0 (c uniform = 1/32)
    k_sumu <<<dim3(8, B), blk, 0, stream>>>(u, sp0);
    k_ot   <<<dim3(NC * (B / 4)), blk, 0, stream>>>(W, sp0, t, 0);
    // iteration 1 (logits + softmax + aggregate fused)
    k_route<<<dim3(IN / RTILE, B), blk, 0, stream>>>(u, t, sp);
    k_ot   <<<dim3(NC * (B / 4)), blk, 0, stream>>>(W, sp, t, 1);
    // iteration 2
    k_route<<<dim3(IN / RTILE, B), blk, 0, stream>>>(u, t, sp);
    k_ot   <<<dim3(NC * (B / 4)), blk, 0, stream>>>(W, sp, out, 2);
}